// Round 10
// baseline (390.151 us; speedup 1.0000x reference)
//
#include <hip/hip_runtime.h>
#include <hip/hip_bf16.h>
#include <math.h>

#define NN 50000
#define NE 800000
#define NB 391          // buckets of 128 nodes: ceil(50000/128)
#define EPB 6250        // edges per bscat/bhist block (128 blocks)

typedef short bf16x8 __attribute__((ext_vector_type(8)));
typedef float f32x4 __attribute__((ext_vector_type(4)));
typedef unsigned short us4 __attribute__((ext_vector_type(4)));
typedef unsigned short us8 __attribute__((ext_vector_type(8)));
typedef unsigned int u32x4 __attribute__((ext_vector_type(4)));

__device__ __forceinline__ float bf2f(unsigned short u) {
  union { unsigned int i; float f; } x; x.i = ((unsigned int)u) << 16; return x.f;
}
__device__ __forceinline__ unsigned short f2bf(float f) {
  union { float f; unsigned int i; } x; x.f = f;
  unsigned int i = x.i;
  unsigned int r = i + 0x7FFF + ((i >> 16) & 1);   // round-to-nearest-even
  return (unsigned short)(r >> 16);
}
__device__ __forceinline__ us4 pack4(f32x4 v) {
  us4 o; o[0] = f2bf(v[0]); o[1] = f2bf(v[1]); o[2] = f2bf(v[2]); o[3] = f2bf(v[3]);
  return o;
}

// ---------------- CSR build, bucketed (all random scatter kept in LDS) --------
__global__ __launch_bounds__(512) void bscan_kernel(const int* __restrict__ bhist,
                                                    int* __restrict__ bucket_off,
                                                    int* __restrict__ gcur) {
  __shared__ int s[512];
  int t = threadIdx.x;
  int v = (t < NB) ? bhist[t] : 0;
  s[t] = v; __syncthreads();
  for (int off = 1; off < 512; off <<= 1) {
    int x = (t >= off) ? s[t - off] : 0;
    __syncthreads();
    s[t] += x;
    __syncthreads();
  }
  if (t < NB) { bucket_off[t] = s[t] - v; gcur[t] = 0; }
  if (t == NB - 1) bucket_off[NB] = s[t];
}

__global__ __launch_bounds__(256) void bscat_kernel(const int* __restrict__ srcn,
                                                    const int* __restrict__ dstn,
                                                    const int* __restrict__ bucket_off,
                                                    int* __restrict__ gcur,
                                                    unsigned long long* __restrict__ ebuf) {
  __shared__ int hist[NB];
  __shared__ int base[NB];
  for (int i = threadIdx.x; i < NB; i += 256) hist[i] = 0;
  __syncthreads();
  int e0 = blockIdx.x * EPB;
  for (int i = threadIdx.x; i < EPB; i += 256)
    atomicAdd(&hist[dstn[e0 + i] >> 7], 1);
  __syncthreads();
  for (int i = threadIdx.x; i < NB; i += 256) {
    int c = hist[i];
    base[i] = c ? (bucket_off[i] + atomicAdd(&gcur[i], c)) : 0;
  }
  __syncthreads();
  for (int i = threadIdx.x; i < EPB; i += 256) {
    int s = srcn[e0 + i], d = dstn[e0 + i];
    int b = d >> 7;
    int pos = atomicSub(&hist[b], 1) - 1;   // order within slice irrelevant
    ebuf[(size_t)base[b] + pos] = ((unsigned long long)(unsigned)d << 32) | (unsigned)s;
  }
}

__global__ __launch_bounds__(256) void bfill_kernel(const unsigned long long* __restrict__ ebuf,
                                                    const int* __restrict__ bucket_off,
                                                    int* __restrict__ rowoff,
                                                    int* __restrict__ csr) {
  int b = blockIdx.x;
  int bo = bucket_off[b], cnt = bucket_off[b + 1] - bo;
  __shared__ int ndeg[128], noff[128];
  int t = threadIdx.x;
  if (t < 128) ndeg[t] = 0;
  __syncthreads();
  for (int i = t; i < cnt; i += 256)
    atomicAdd(&ndeg[(int)(ebuf[bo + i] >> 32) & 127], 1);
  __syncthreads();
  if (t < 128) noff[t] = ndeg[t];
  __syncthreads();
  for (int off = 1; off < 128; off <<= 1) {   // inclusive scan (Hillis-Steele)
    int x = 0;
    if (t < 128 && t >= off) x = noff[t - off];
    __syncthreads();
    if (t < 128 && t >= off) noff[t] += x;
    __syncthreads();
  }
  if (t < 128) {
    int ex = noff[t] - ndeg[t];    // exclusive
    noff[t] = ex;
    int node = b * 128 + t;
    if (node < NN) rowoff[node] = bo + ex;
  }
  if (b == NB - 1 && t == 0) rowoff[NN] = NE;
  __syncthreads();
  for (int i = t; i < cnt; i += 256) {
    unsigned long long e = ebuf[bo + i];
    int dl = (int)(e >> 32) & 127;
    int pos = atomicSub(&ndeg[dl], 1) - 1;
    csr[bo + noff[dl] + pos] = (int)(unsigned)e;
  }
}

// ---------------- fused setup: convz (6250 blocks) | prep (64) | bhist (128) ----
// convz dual-writes: row-major A1 right half AND slice layout ts[p][node][32]
__global__ __launch_bounds__(256) void setup_kernel(
    const float* __restrict__ z, unsigned short* __restrict__ A1,
    unsigned short* __restrict__ ts,
    const float* __restrict__ w1n, const float* __restrict__ w1r,
    const float* __restrict__ w2n, const float* __restrict__ w2r,
    const float* __restrict__ wfn, const float* __restrict__ wfr,
    const float* __restrict__ wr1, const float* __restrict__ wr2,
    unsigned short* __restrict__ Bp1, unsigned short* __restrict__ Bp2,
    unsigned short* __restrict__ Bp3,
    const int* __restrict__ dstn, int* __restrict__ bhist) {
  __shared__ int h[NB];
  int b = blockIdx.x;
  if (b < 6250) {               // ---- convz
    int i = b * 256 + threadIdx.x;   // groups of 4 elements
    if (i >= NN * 128 / 4) return;
    int i4 = i * 4;
    int row = i4 >> 7, c = i4 & 127;
    f32x4 v = *(const f32x4*)(z + i4);
    us4 o = { f2bf(v[0]), f2bf(v[1]), f2bf(v[2]), f2bf(v[3]) };
    *(us4*)(A1 + (size_t)row * 256 + 128 + c) = o;
    *(us4*)(ts + ((size_t)(c >> 5) * NN + row) * 32 + (c & 31)) = o;
  } else if (b < 6314) {        // ---- prep: pack B into MFMA fragment-major
    int g = (b - 6250) * 256 + threadIdx.x;
    unsigned short* D; int NT, fi;
    int which;  // 1,2,3
    if      (g < 10240) { fi = g;         D = Bp1; NT = 20; which = 1; }
    else if (g < 14336) { fi = g - 10240; D = Bp2; NT = 8;  which = 2; }
    else if (g < 16384) { fi = g - 14336; D = Bp3; NT = 4;  which = 3; }
    else return;
    int lane = fi & 63, t = fi >> 6;
    int nt = t % NT, k0i = t / NT;
    int m = lane & 15, q = lane >> 4;
    int kb = k0i * 32 + q * 8;          // 8-aligned: all j on same side of 128
    int n = nt * 16 + m;
    int hi = (kb >= 128);
    int k0_ = kb - (hi ? 128 : 0);
    const float* W = nullptr; int Nseg = 128; int nn = n;
    if (which == 1) {
      if (n < 128)      { W = hi ? w1r : w1n; nn = n; Nseg = 128; }
      else if (n < 256) { W = hi ? wr1 : nullptr; nn = n - 128; Nseg = 128; }
      else              { W = hi ? wr2 : nullptr; nn = n - 256; Nseg = 64; }
    } else if (which == 2) { W = hi ? w2r : w2n; Nseg = 128; }
    else                   { W = hi ? wfr : wfn; Nseg = 64; }
    unsigned short o[8];
#pragma unroll
    for (int j = 0; j < 8; j++)
      o[j] = W ? f2bf(W[(size_t)(k0_ + j) * Nseg + nn]) : (unsigned short)0;
    *(us8*)(D + (size_t)fi * 8) = *(const us8*)o;
  } else {                      // ---- bhist
    for (int i = threadIdx.x; i < NB; i += 256) h[i] = 0;
    __syncthreads();
    int e0 = (b - 6314) * EPB;
    for (int i = threadIdx.x; i < EPB; i += 256)
      atomicAdd(&h[dstn[e0 + i] >> 7], 1);
    __syncthreads();
    for (int i = threadIdx.x; i < NB; i += 256)
      if (h[i]) atomicAdd(&bhist[i], h[i]);
  }
}

// ---------------- mean aggregation: column-sliced 4-pass gather -----------------
// Pass p (blockIdx.y, x-fastest dispatch keeps one pass resident at a time)
// gathers from ts[p][node][32] — 3.2 MB slice, L2-resident. One wave per node,
// 4 subgroups of 16 lanes, 4 B/lane, branchless 4-deep clamped tail.
__global__ __launch_bounds__(256) void agg_kernel(const unsigned short* __restrict__ ts,
                                                  unsigned short* __restrict__ outm, int ostride,
                                                  const int* __restrict__ rowoff,
                                                  const int* __restrict__ csr) {
  int p = blockIdx.y;
  const unsigned short* sl = ts + (size_t)p * NN * 32;
  int wave = threadIdx.x >> 6, lane = threadIdx.x & 63;
  int node = blockIdx.x * 4 + wave;
  if (node >= NN) return;
  int beg = rowoff[node], end = rowoff[node + 1];
  int g = lane >> 4;           // neighbor subgroup 0..3
  int c = (lane & 15) << 1;    // 2 bf16 = 4 B per lane
  float a0 = 0.f, a1 = 0.f;
  int e1 = end - 1;
  for (int j = beg + g; j < end; j += 16) {
    int j1 = (j + 4 < e1) ? j + 4 : e1;
    int j2 = (j + 8 < e1) ? j + 8 : e1;
    int j3 = (j + 12 < e1) ? j + 12 : e1;
    int s0 = csr[j], s1 = csr[j1], s2 = csr[j2], s3 = csr[j3];
    float w1 = (j + 4 < end) ? 1.f : 0.f;
    float w2 = (j + 8 < end) ? 1.f : 0.f;
    float w3 = (j + 12 < end) ? 1.f : 0.f;
    unsigned int v0 = *(const unsigned int*)(sl + (size_t)s0 * 32 + c);
    unsigned int v1 = *(const unsigned int*)(sl + (size_t)s1 * 32 + c);
    unsigned int v2 = *(const unsigned int*)(sl + (size_t)s2 * 32 + c);
    unsigned int v3 = *(const unsigned int*)(sl + (size_t)s3 * 32 + c);
    float l0 = bf2f((unsigned short)(v0 & 0xffff));
    float h0 = bf2f((unsigned short)(v0 >> 16));
    l0 = fmaf(w1, bf2f((unsigned short)(v1 & 0xffff)), l0);
    h0 = fmaf(w1, bf2f((unsigned short)(v1 >> 16)), h0);
    l0 = fmaf(w2, bf2f((unsigned short)(v2 & 0xffff)), l0);
    h0 = fmaf(w2, bf2f((unsigned short)(v2 >> 16)), h0);
    l0 = fmaf(w3, bf2f((unsigned short)(v3 & 0xffff)), l0);
    h0 = fmaf(w3, bf2f((unsigned short)(v3 >> 16)), h0);
    a0 += l0; a1 += h0;
  }
  a0 += __shfl_xor(a0, 16, 64); a0 += __shfl_xor(a0, 32, 64);
  a1 += __shfl_xor(a1, 16, 64); a1 += __shfl_xor(a1, 32, 64);
  if (g == 0) {
    float inv = 1.f / fmaxf((float)(end - beg), 1.f);
    unsigned int o = ((unsigned int)f2bf(a1 * inv) << 16) | f2bf(a0 * inv);
    *(unsigned int*)(outm + (size_t)node * ostride + p * 32 + c) = o;
  }
}

// ---------------- GEMM1: A1[NN x 256] @ Bp1(NT=20) -> h1(+ts) | res1 | res2 ------
__global__ __launch_bounds__(256) void gemm1_kernel(
    const unsigned short* __restrict__ A,
    const unsigned short* __restrict__ Bp,
    const float* __restrict__ b1, const float* __restrict__ br1, const float* __restrict__ br2,
    unsigned short* __restrict__ h1out,   // A2+128, stride 256
    unsigned short* __restrict__ ts,      // slice layout for next agg
    unsigned short* __restrict__ res1, unsigned short* __restrict__ res2)
{
  const int NT = 20, TILES = 5;
  __shared__ unsigned short Bs[TILES * 8 * 512];   // 40 KB
  int tid = threadIdx.x;
  int wave = tid >> 6, lane = tid & 63;
  int ybase = blockIdx.x * TILES;
  int row0 = blockIdx.y * 128 + wave * 16;
  int m = lane & 15, q = lane >> 4;
  const unsigned short* arow0 = A + (size_t)(row0 + m) * 256 + q * 8;
  const unsigned short* arow1 = arow0 + 64 * 256;
  bf16x8 af0[8], af1[8];
#pragma unroll
  for (int k0i = 0; k0i < 8; ++k0i) {
    af0[k0i] = *(const bf16x8*)(arow0 + k0i * 32);
    af1[k0i] = *(const bf16x8*)(arow1 + k0i * 32);
  }
#pragma unroll
  for (int i = tid; i < TILES * 64 * 8; i += 256) {     // us8 copies
    int k0i = i / (TILES * 64), r = i % (TILES * 64);
    *(us8*)(Bs + (size_t)k0i * TILES * 512 + (size_t)r * 8) =
        *(const us8*)(Bp + ((size_t)k0i * NT + ybase) * 512 + (size_t)r * 8);
  }
  __syncthreads();
  f32x4 acc[2][TILES];
#pragma unroll
  for (int h = 0; h < 2; h++)
#pragma unroll
    for (int i = 0; i < TILES; i++) acc[h][i] = (f32x4){0.f, 0.f, 0.f, 0.f};
#pragma unroll
  for (int k0i = 0; k0i < 8; ++k0i) {
    const unsigned short* bk = Bs + (size_t)k0i * TILES * 512 + lane * 8;
#pragma unroll
    for (int s = 0; s < TILES; ++s) {
      bf16x8 bfr = *(const bf16x8*)(bk + s * 512);
      acc[0][s] = __builtin_amdgcn_mfma_f32_16x16x32_bf16(bfr, af0[k0i], acc[0][s], 0, 0, 0);
      acc[1][s] = __builtin_amdgcn_mfma_f32_16x16x32_bf16(bfr, af1[k0i], acc[1][s], 0, 0, 0);
    }
  }
  int cb = q * 4;
#pragma unroll
  for (int h = 0; h < 2; h++) {
    int row = row0 + h * 64 + m;
    if (row >= NN) continue;
#pragma unroll
    for (int s = 0; s < TILES; ++s) {
      int nt = ybase + s;
      f32x4 v = acc[h][s];
      if (nt < 8) {
        int col = nt * 16 + cb;
        f32x4 bb = *(const f32x4*)(b1 + col);
        v[0] = fmaxf(v[0] + bb[0], 0.f); v[1] = fmaxf(v[1] + bb[1], 0.f);
        v[2] = fmaxf(v[2] + bb[2], 0.f); v[3] = fmaxf(v[3] + bb[3], 0.f);
        us4 pk = pack4(v);
        *(us4*)(h1out + (size_t)row * 256 + col) = pk;
        *(us4*)(ts + ((size_t)(col >> 5) * NN + row) * 32 + (col & 31)) = pk;
      } else if (nt < 16) {
        int col = (nt - 8) * 16 + cb;
        f32x4 bb = *(const f32x4*)(br1 + col);
        v[0] += bb[0]; v[1] += bb[1]; v[2] += bb[2]; v[3] += bb[3];
        *(us4*)(res1 + (size_t)row * 128 + col) = pack4(v);
      } else {
        int col = (nt - 16) * 16 + cb;
        f32x4 bb = *(const f32x4*)(br2 + col);
        v[0] += bb[0]; v[1] += bb[1]; v[2] += bb[2]; v[3] += bb[3];
        *(us4*)(res2 + (size_t)row * 64 + col) = pack4(v);
      }
    }
  }
}

// ---------------- GEMM2/3: A[NN x 256] @ Bp -> out (+bias, +res(bf16), relu/sig8) -
template <int NTT, int RPW>
__global__ __launch_bounds__(256) void gemm23_kernel(
    const unsigned short* __restrict__ A,
    const unsigned short* __restrict__ Bp,
    const float* __restrict__ bias,
    const unsigned short* __restrict__ res, int res_stride,
    unsigned short* __restrict__ out_bf,   // stride 256, may be null
    unsigned short* __restrict__ ts,       // slice dual-write (may be null)
    float* __restrict__ out_f, int of_stride,
    int relu, int sig8)
{
  const int TILES = 4;
  __shared__ unsigned short Bs[TILES * 8 * 512];   // 32 KB
  int tid = threadIdx.x;
  int wave = tid >> 6, lane = tid & 63;
  int ybase = blockIdx.x * TILES;
  int row0 = blockIdx.y * (64 * RPW) + wave * 16;
  int m = lane & 15, q = lane >> 4;
  bf16x8 af[RPW][8];
#pragma unroll
  for (int h = 0; h < RPW; h++) {
    const unsigned short* arow = A + (size_t)(row0 + h * 64 + m) * 256 + q * 8;
#pragma unroll
    for (int k0i = 0; k0i < 8; ++k0i) af[h][k0i] = *(const bf16x8*)(arow + k0i * 32);
  }
#pragma unroll
  for (int i = tid; i < TILES * 64 * 8; i += 256) {
    int k0i = i / (TILES * 64), r = i % (TILES * 64);
    *(us8*)(Bs + (size_t)k0i * TILES * 512 + (size_t)r * 8) =
        *(const us8*)(Bp + ((size_t)k0i * NTT + ybase) * 512 + (size_t)r * 8);
  }
  __syncthreads();
  f32x4 acc[RPW][TILES];
#pragma unroll
  for (int h = 0; h < RPW; h++)
#pragma unroll
    for (int i = 0; i < TILES; i++) acc[h][i] = (f32x4){0.f, 0.f, 0.f, 0.f};
#pragma unroll
  for (int k0i = 0; k0i < 8; ++k0i) {
    const unsigned short* bk = Bs + (size_t)k0i * TILES * 512 + lane * 8;
#pragma unroll
    for (int s = 0; s < TILES; ++s) {
      bf16x8 bfr = *(const bf16x8*)(bk + s * 512);
#pragma unroll
      for (int h = 0; h < RPW; h++)
        acc[h][s] = __builtin_amdgcn_mfma_f32_16x16x32_bf16(bfr, af[h][k0i], acc[h][s], 0, 0, 0);
    }
  }
  int cb = q * 4;
#pragma unroll
  for (int h = 0; h < RPW; h++) {
    int row = row0 + h * 64 + m;
    if (row >= NN) continue;
#pragma unroll
    for (int s = 0; s < TILES; ++s) {
      int col = (ybase + s) * 16 + cb;
      f32x4 v = acc[h][s];
      f32x4 bb = *(const f32x4*)(bias + col);
      v[0] += bb[0]; v[1] += bb[1]; v[2] += bb[2]; v[3] += bb[3];
      if (relu) {
#pragma unroll
        for (int r = 0; r < 4; r++) v[r] = fmaxf(v[r], 0.f);
      }
      if (res) {
        us4 rv = *(const us4*)(res + (size_t)row * res_stride + col);
#pragma unroll
        for (int r = 0; r < 4; r++) v[r] += bf2f(rv[r]);
      }
      if (sig8 && col < 8) {
#pragma unroll
        for (int r = 0; r < 4; r++) v[r] = 1.f / (1.f + __expf(-v[r]));
      }
      if (out_bf) {
        us4 pk = pack4(v);
        *(us4*)(out_bf + (size_t)row * 256 + col) = pk;
        if (ts) *(us4*)(ts + ((size_t)(col >> 5) * NN + row) * 32 + (col & 31)) = pk;
      }
      if (out_f)
        *(f32x4*)(out_f + (size_t)row * of_stride + col) = v;
    }
  }
}

extern "C" void kernel_launch(void* const* d_in, const int* in_sizes, int n_in,
                              void* d_out, int out_size, void* d_ws, size_t ws_size,
                              hipStream_t stream) {
  const float* z   = (const float*)d_in[0];
  const int*   edge = (const int*)d_in[1];
  const int*   srcn = edge;        // edge_index[0]
  const int*   dstn = edge + NE;   // edge_index[1]
  const float* w1n = (const float*)d_in[2];
  const float* w1r = (const float*)d_in[3];
  const float* b1  = (const float*)d_in[4];
  const float* w2n = (const float*)d_in[5];
  const float* w2r = (const float*)d_in[6];
  const float* b2  = (const float*)d_in[7];
  const float* wfn = (const float*)d_in[8];
  const float* wfr = (const float*)d_in[9];
  const float* bfb = (const float*)d_in[10];
  const float* wr1 = (const float*)d_in[11];
  const float* br1 = (const float*)d_in[12];
  const float* wr2 = (const float*)d_in[13];
  const float* br2 = (const float*)d_in[14];
  float* out = (float*)d_out;

  char* p = (char*)d_ws;
  auto alloc = [&](size_t bytes) { char* r = p; p += (bytes + 255) & ~255ull; return r; };
  int* rowoff = (int*)alloc((size_t)(NN + 1) * 4);
  int* bhist  = (int*)alloc((size_t)NB * 4);
  int* bucket_off = (int*)alloc((size_t)(NB + 1) * 4);
  int* gcur   = (int*)alloc((size_t)NB * 4);
  int* csr    = (int*)alloc((size_t)NE * 4);
  unsigned short* A1 = (unsigned short*)alloc((size_t)NN * 256 * 2);  // [mean1|z_bf], later reused as A3
  unsigned short* A2 = (unsigned short*)alloc((size_t)NN * 256 * 2);  // [mean2|h1]
  unsigned short* ts = (unsigned short*)alloc((size_t)NN * 128 * 2);  // 4 x (NN x 32) slices
  unsigned short* res1 = (unsigned short*)alloc((size_t)NN * 128 * 2);
  unsigned short* res2 = (unsigned short*)alloc((size_t)NN * 64 * 2);
  unsigned short* Bp1 = (unsigned short*)alloc(10240 * 8 * 2);
  unsigned short* Bp2 = (unsigned short*)alloc(4096 * 8 * 2);
  unsigned short* Bp3 = (unsigned short*)alloc(2048 * 8 * 2);
  unsigned short* A3 = A1;  // alias: A1 dead once gemm1 outputs land
  // ebuf aliases res1 (6.4 MB <= 12.8 MB): dead before gemm1 writes res1
  unsigned long long* ebuf = (unsigned long long*)res1;

  hipMemsetAsync(bhist, 0, (size_t)NB * 4, stream);
  // fused prologue: convz (dual-write A1 + ts) | prep | bhist
  setup_kernel<<<6442, 256, 0, stream>>>(z, A1, ts, w1n, w1r, w2n, w2r, wfn, wfr, wr1, wr2,
                                         Bp1, Bp2, Bp3, dstn, bhist);
  bscan_kernel<<<1, 512, 0, stream>>>(bhist, bucket_off, gcur);
  bscat_kernel<<<128, 256, 0, stream>>>(srcn, dstn, bucket_off, gcur, ebuf);
  bfill_kernel<<<NB, 256, 0, stream>>>(ebuf, bucket_off, rowoff, csr);

  const int gy128 = (NN + 127) / 128;   // 391
  const int gy64  = (NN + 63) / 64;     // 782
  const int aggx = (NN + 3) / 4;        // 12500

  // layer 1: mean1 = agg(ts(z)); fused GEMM -> h1 (A2 right + ts), res1, res2
  agg_kernel<<<dim3(aggx, 4), 256, 0, stream>>>(ts, A1, 256, rowoff, csr);
  gemm1_kernel<<<dim3(4, gy128), 256, 0, stream>>>(A1, Bp1, b1, br1, br2,
      A2 + 128, ts, res1, res2);

  // layer 2: mean2 = agg(ts(h1)); h2 = relu([mean2|h1]@W2+b2) + res1 -> A3 right + ts
  agg_kernel<<<dim3(aggx, 4), 256, 0, stream>>>(ts, A2, 256, rowoff, csr);
  gemm23_kernel<8, 2><<<dim3(2, gy128), 256, 0, stream>>>(A2, Bp2, b2, res1, 128,
      A3 + 128, ts, nullptr, 0, 1, 0);

  // layer 3: mean3 = agg(ts(h2)); out = [mean3|h2]@Wf+bf + res2, sigmoid cols 0..7
  agg_kernel<<<dim3(aggx, 4), 256, 0, stream>>>(ts, A3, 256, rowoff, csr);
  gemm23_kernel<4, 1><<<dim3(1, gy64), 256, 0, stream>>>(A3, Bp3, bfb, res2, 64,
      nullptr, nullptr, out, 64, 0, 1);
}

// Round 11
// 282.317 us; speedup vs baseline: 1.3820x; 1.3820x over previous
//
#include <hip/hip_runtime.h>
#include <hip/hip_bf16.h>
#include <math.h>

#define NN 50000
#define NE 800000
#define NB 391          // buckets of 128 nodes: ceil(50000/128)
#define EPB 6250        // edges per bscat/bhist block (128 blocks)

typedef short bf16x8 __attribute__((ext_vector_type(8)));
typedef float f32x4 __attribute__((ext_vector_type(4)));
typedef unsigned short us4 __attribute__((ext_vector_type(4)));
typedef unsigned short us8 __attribute__((ext_vector_type(8)));
typedef unsigned int u32x4 __attribute__((ext_vector_type(4)));

__device__ __forceinline__ float bf2f(unsigned short u) {
  union { unsigned int i; float f; } x; x.i = ((unsigned int)u) << 16; return x.f;
}
__device__ __forceinline__ unsigned short f2bf(float f) {
  union { float f; unsigned int i; } x; x.f = f;
  unsigned int i = x.i;
  unsigned int r = i + 0x7FFF + ((i >> 16) & 1);   // round-to-nearest-even
  return (unsigned short)(r >> 16);
}
__device__ __forceinline__ unsigned long long pk64(f32x4 v) {
  union { us4 s; unsigned long long u; } x;
  x.s[0] = f2bf(v[0]); x.s[1] = f2bf(v[1]); x.s[2] = f2bf(v[2]); x.s[3] = f2bf(v[3]);
  return x.u;
}
__device__ __forceinline__ us4 pack4(f32x4 v) {
  us4 o; o[0] = f2bf(v[0]); o[1] = f2bf(v[1]); o[2] = f2bf(v[2]); o[3] = f2bf(v[3]);
  return o;
}

// ---------------- CSR build, bucketed (all random scatter kept in LDS) --------
__global__ __launch_bounds__(512) void bscan_kernel(const int* __restrict__ bhist,
                                                    int* __restrict__ bucket_off,
                                                    int* __restrict__ gcur) {
  __shared__ int s[512];
  int t = threadIdx.x;
  int v = (t < NB) ? bhist[t] : 0;
  s[t] = v; __syncthreads();
  for (int off = 1; off < 512; off <<= 1) {
    int x = (t >= off) ? s[t - off] : 0;
    __syncthreads();
    s[t] += x;
    __syncthreads();
  }
  if (t < NB) { bucket_off[t] = s[t] - v; gcur[t] = 0; }
  if (t == NB - 1) bucket_off[NB] = s[t];
}

__global__ __launch_bounds__(256) void bscat_kernel(const int* __restrict__ srcn,
                                                    const int* __restrict__ dstn,
                                                    const int* __restrict__ bucket_off,
                                                    int* __restrict__ gcur,
                                                    unsigned long long* __restrict__ ebuf) {
  __shared__ int hist[NB];
  __shared__ int base[NB];
  for (int i = threadIdx.x; i < NB; i += 256) hist[i] = 0;
  __syncthreads();
  int e0 = blockIdx.x * EPB;
  for (int i = threadIdx.x; i < EPB; i += 256)
    atomicAdd(&hist[dstn[e0 + i] >> 7], 1);
  __syncthreads();
  for (int i = threadIdx.x; i < NB; i += 256) {
    int c = hist[i];
    base[i] = c ? (bucket_off[i] + atomicAdd(&gcur[i], c)) : 0;
  }
  __syncthreads();
  for (int i = threadIdx.x; i < EPB; i += 256) {
    int s = srcn[e0 + i], d = dstn[e0 + i];
    int b = d >> 7;
    int pos = atomicSub(&hist[b], 1) - 1;   // order within slice irrelevant
    ebuf[(size_t)base[b] + pos] = ((unsigned long long)(unsigned)d << 32) | (unsigned)s;
  }
}

__global__ __launch_bounds__(256) void bfill_kernel(const unsigned long long* __restrict__ ebuf,
                                                    const int* __restrict__ bucket_off,
                                                    int* __restrict__ rowoff,
                                                    int* __restrict__ csr) {
  int b = blockIdx.x;
  int bo = bucket_off[b], cnt = bucket_off[b + 1] - bo;
  __shared__ int ndeg[128], noff[128];
  int t = threadIdx.x;
  if (t < 128) ndeg[t] = 0;
  __syncthreads();
  for (int i = t; i < cnt; i += 256)
    atomicAdd(&ndeg[(int)(ebuf[bo + i] >> 32) & 127], 1);
  __syncthreads();
  if (t < 128) noff[t] = ndeg[t];
  __syncthreads();
  for (int off = 1; off < 128; off <<= 1) {   // inclusive scan (Hillis-Steele)
    int x = 0;
    if (t < 128 && t >= off) x = noff[t - off];
    __syncthreads();
    if (t < 128 && t >= off) noff[t] += x;
    __syncthreads();
  }
  if (t < 128) {
    int ex = noff[t] - ndeg[t];    // exclusive
    noff[t] = ex;
    int node = b * 128 + t;
    if (node < NN) rowoff[node] = bo + ex;
  }
  if (b == NB - 1 && t == 0) rowoff[NN] = NE;
  __syncthreads();
  for (int i = t; i < cnt; i += 256) {
    unsigned long long e = ebuf[bo + i];
    int dl = (int)(e >> 32) & 127;
    int pos = atomicSub(&ndeg[dl], 1) - 1;
    csr[bo + noff[dl] + pos] = (int)(unsigned)e;
  }
}

// ---------------- fused setup: convz (6250 blocks) | prep (64) | bhist (128) ----
__global__ __launch_bounds__(256) void setup_kernel(
    const float* __restrict__ z, unsigned short* __restrict__ A1,
    const float* __restrict__ w1n, const float* __restrict__ w1r,
    const float* __restrict__ w2n, const float* __restrict__ w2r,
    const float* __restrict__ wfn, const float* __restrict__ wfr,
    const float* __restrict__ wr1, const float* __restrict__ wr2,
    unsigned short* __restrict__ Bp1, unsigned short* __restrict__ Bp2,
    unsigned short* __restrict__ Bp3,
    const int* __restrict__ dstn, int* __restrict__ bhist) {
  __shared__ int h[NB];
  int b = blockIdx.x;
  if (b < 6250) {               // ---- convz: z (f32) -> bf16 into A1 right half
    int i = b * 256 + threadIdx.x;   // groups of 4 elements
    if (i >= NN * 128 / 4) return;
    int i4 = i * 4;
    int row = i4 >> 7, c = i4 & 127;
    f32x4 v = *(const f32x4*)(z + i4);
    us4 o = { f2bf(v[0]), f2bf(v[1]), f2bf(v[2]), f2bf(v[3]) };
    *(us4*)(A1 + (size_t)row * 256 + 128 + c) = o;
  } else if (b < 6314) {        // ---- prep: pack B into MFMA fragment-major
    int g = (b - 6250) * 256 + threadIdx.x;
    unsigned short* D; int NT, fi;
    int which;  // 1,2,3
    if      (g < 10240) { fi = g;         D = Bp1; NT = 20; which = 1; }
    else if (g < 14336) { fi = g - 10240; D = Bp2; NT = 8;  which = 2; }
    else if (g < 16384) { fi = g - 14336; D = Bp3; NT = 4;  which = 3; }
    else return;
    int lane = fi & 63, t = fi >> 6;
    int nt = t % NT, k0i = t / NT;
    int m = lane & 15, q = lane >> 4;
    int kb = k0i * 32 + q * 8;          // 8-aligned: all j on same side of 128
    int n = nt * 16 + m;
    int hi = (kb >= 128);
    int k0_ = kb - (hi ? 128 : 0);
    const float* W = nullptr; int Nseg = 128; int nn = n;
    if (which == 1) {
      if (n < 128)      { W = hi ? w1r : w1n; nn = n; Nseg = 128; }
      else if (n < 256) { W = hi ? wr1 : nullptr; nn = n - 128; Nseg = 128; }
      else              { W = hi ? wr2 : nullptr; nn = n - 256; Nseg = 64; }
    } else if (which == 2) { W = hi ? w2r : w2n; Nseg = 128; }
    else                   { W = hi ? wfr : wfn; Nseg = 64; }
    unsigned short o[8];
#pragma unroll
    for (int j = 0; j < 8; j++)
      o[j] = W ? f2bf(W[(size_t)(k0_ + j) * Nseg + nn]) : (unsigned short)0;
    *(us8*)(D + (size_t)fi * 8) = *(const us8*)o;
  } else {                      // ---- bhist
    for (int i = threadIdx.x; i < NB; i += 256) h[i] = 0;
    __syncthreads();
    int e0 = (b - 6314) * EPB;
    for (int i = threadIdx.x; i < EPB; i += 256)
      atomicAdd(&h[dstn[e0 + i] >> 7], 1);
    __syncthreads();
    for (int i = threadIdx.x; i < NB; i += 256)
      if (h[i]) atomicAdd(&bhist[i], h[i]);
  }
}

// ---------------- mean aggregation: one wave per node, branchless 4-deep tail ---
__global__ __launch_bounds__(256) void agg_kernel(const unsigned short* __restrict__ feat, int fstride,
                                                  unsigned short* __restrict__ outm, int ostride,
                                                  const int* __restrict__ rowoff,
                                                  const int* __restrict__ csr) {
  int wave = threadIdx.x >> 6, lane = threadIdx.x & 63;
  int node = blockIdx.x * 4 + wave;
  if (node >= NN) return;
  int beg = rowoff[node], end = rowoff[node + 1];
  int g = lane >> 4;           // neighbor subgroup 0..3
  int c = (lane & 15) << 3;    // column offset (8 bf16 = 16B per lane)
  float a[8];
#pragma unroll
  for (int i = 0; i < 8; i++) a[i] = 0.f;
  int e1 = end - 1;
  for (int j = beg + g; j < end; j += 16) {
    int j1 = (j + 4 < e1) ? j + 4 : e1;
    int j2 = (j + 8 < e1) ? j + 8 : e1;
    int j3 = (j + 12 < e1) ? j + 12 : e1;
    int s0 = csr[j], s1 = csr[j1], s2 = csr[j2], s3 = csr[j3];
    float w1 = (j + 4 < end) ? 1.f : 0.f;
    float w2 = (j + 8 < end) ? 1.f : 0.f;
    float w3 = (j + 12 < end) ? 1.f : 0.f;
    u32x4 v0 = *(const u32x4*)(feat + (size_t)s0 * fstride + c);
    u32x4 v1 = *(const u32x4*)(feat + (size_t)s1 * fstride + c);
    u32x4 v2 = *(const u32x4*)(feat + (size_t)s2 * fstride + c);
    u32x4 v3 = *(const u32x4*)(feat + (size_t)s3 * fstride + c);
#pragma unroll
    for (int i = 0; i < 4; i++) {
      float l0 = bf2f((unsigned short)(v0[i] & 0xffff));
      float h0 = bf2f((unsigned short)(v0[i] >> 16));
      l0 = fmaf(w1, bf2f((unsigned short)(v1[i] & 0xffff)), l0);
      h0 = fmaf(w1, bf2f((unsigned short)(v1[i] >> 16)), h0);
      l0 = fmaf(w2, bf2f((unsigned short)(v2[i] & 0xffff)), l0);
      h0 = fmaf(w2, bf2f((unsigned short)(v2[i] >> 16)), h0);
      l0 = fmaf(w3, bf2f((unsigned short)(v3[i] & 0xffff)), l0);
      h0 = fmaf(w3, bf2f((unsigned short)(v3[i] >> 16)), h0);
      a[2*i] += l0;
      a[2*i+1] += h0;
    }
  }
#pragma unroll
  for (int i = 0; i < 8; i++) {
    a[i] += __shfl_xor(a[i], 16, 64);
    a[i] += __shfl_xor(a[i], 32, 64);
  }
  if (g == 0) {
    float inv = 1.f / fmaxf((float)(end - beg), 1.f);
    unsigned int o[4];
#pragma unroll
    for (int i = 0; i < 4; i++)
      o[i] = ((unsigned int)f2bf(a[2*i+1] * inv) << 16) | f2bf(a[2*i] * inv);
    *(u32x4*)(outm + (size_t)node * ostride + c) = *(const u32x4*)o;
  }
}

// ---------------- GEMM1: A1[NN x 256] @ Bp1(NT=20) -> h1 | res1 | res2 ----------
// grid (5, 391): x picks 4 tiles = ONE destination per block. Pair-shuffle
// epilogue: tiles (0,1) and (2,3) combined via cross-lane shuffle so each lane
// stores 16 B contiguous -> 16 rows x 64 B full-line write transactions.
__global__ __launch_bounds__(256) void gemm1_kernel(
    const unsigned short* __restrict__ A,
    const unsigned short* __restrict__ Bp,
    const float* __restrict__ b1, const float* __restrict__ br1, const float* __restrict__ br2,
    unsigned short* __restrict__ h1out,   // A2+128, stride 256
    unsigned short* __restrict__ res1, unsigned short* __restrict__ res2)
{
  const int NT = 20, TILES = 4;
  __shared__ unsigned short Bs[TILES * 8 * 512];   // 32 KB
  int tid = threadIdx.x;
  int wave = tid >> 6, lane = tid & 63;
  int xg = blockIdx.x;
  int ybase = xg * TILES;
  int row0 = blockIdx.y * 128 + wave * 16;
  int m = lane & 15, q = lane >> 4;
  // block-uniform destination select
  const float* bias; unsigned short* dst; int dstride, cbb; int relu;
  if (xg < 2)      { bias = b1 + xg * 64;        dst = h1out; dstride = 256; cbb = xg * 64;        relu = 1; }
  else if (xg < 4) { bias = br1 + (xg - 2) * 64; dst = res1;  dstride = 128; cbb = (xg - 2) * 64;  relu = 0; }
  else             { bias = br2;                 dst = res2;  dstride = 64;  cbb = 0;              relu = 0; }

  const unsigned short* arow0 = A + (size_t)(row0 + m) * 256 + q * 8;
  const unsigned short* arow1 = arow0 + 64 * 256;
  bf16x8 af0[8], af1[8];
#pragma unroll
  for (int k0i = 0; k0i < 8; ++k0i) {
    af0[k0i] = *(const bf16x8*)(arow0 + k0i * 32);
    af1[k0i] = *(const bf16x8*)(arow1 + k0i * 32);
  }
#pragma unroll
  for (int i = tid; i < TILES * 64 * 8; i += 256) {     // us8 copies
    int k0i = i / (TILES * 64), r = i % (TILES * 64);
    *(us8*)(Bs + (size_t)k0i * TILES * 512 + (size_t)r * 8) =
        *(const us8*)(Bp + ((size_t)k0i * NT + ybase) * 512 + (size_t)r * 8);
  }
  __syncthreads();
  f32x4 acc[2][TILES];
#pragma unroll
  for (int h = 0; h < 2; h++)
#pragma unroll
    for (int i = 0; i < TILES; i++) acc[h][i] = (f32x4){0.f, 0.f, 0.f, 0.f};
#pragma unroll
  for (int k0i = 0; k0i < 8; ++k0i) {
    const unsigned short* bk = Bs + (size_t)k0i * TILES * 512 + lane * 8;
#pragma unroll
    for (int s = 0; s < TILES; ++s) {
      bf16x8 bfr = *(const bf16x8*)(bk + s * 512);
      acc[0][s] = __builtin_amdgcn_mfma_f32_16x16x32_bf16(bfr, af0[k0i], acc[0][s], 0, 0, 0);
      acc[1][s] = __builtin_amdgcn_mfma_f32_16x16x32_bf16(bfr, af1[k0i], acc[1][s], 0, 0, 0);
    }
  }
  int src0 = m + ((q & 1) ? 32 : 0);
#pragma unroll
  for (int h = 0; h < 2; h++) {
    int row = row0 + h * 64 + m;
#pragma unroll
    for (int p = 0; p < 2; p++) {
      f32x4 v0 = acc[h][2 * p], v1 = acc[h][2 * p + 1];
      f32x4 bb0 = *(const f32x4*)(bias + 32 * p + 4 * q);
      f32x4 bb1 = *(const f32x4*)(bias + 32 * p + 16 + 4 * q);
#pragma unroll
      for (int r = 0; r < 4; r++) { v0[r] += bb0[r]; v1[r] += bb1[r]; }
      if (relu) {
#pragma unroll
        for (int r = 0; r < 4; r++) { v0[r] = fmaxf(v0[r], 0.f); v1[r] = fmaxf(v1[r], 0.f); }
      }
      unsigned long long d0 = pk64(v0), d1 = pk64(v1);
      unsigned long long a0 = __shfl(d0, src0, 64);
      unsigned long long b0 = __shfl(d0, src0 + 16, 64);
      unsigned long long a1 = __shfl(d1, src0, 64);
      unsigned long long b1v = __shfl(d1, src0 + 16, 64);
      unsigned long long lo = (q >> 1) ? a1 : a0;
      unsigned long long hi = (q >> 1) ? b1v : b0;
      if (row < NN) {
        unsigned long long ov[2] = { lo, hi };
        *(us8*)(dst + (size_t)row * dstride + cbb + 32 * p + 8 * q) = *(const us8*)ov;
      }
    }
  }
}

// ---------------- GEMM2: A2 @ Bp2(NT=8) -> h2 = relu(..)+res1, pair-shuffle ------
__global__ __launch_bounds__(256) void gemm2_kernel(
    const unsigned short* __restrict__ A,
    const unsigned short* __restrict__ Bp,
    const float* __restrict__ b2,
    const unsigned short* __restrict__ res1,   // stride 128
    unsigned short* __restrict__ out_bf)       // A3+128, stride 256
{
  const int NT = 8, TILES = 4;
  __shared__ unsigned short Bs[TILES * 8 * 512];   // 32 KB
  int tid = threadIdx.x;
  int wave = tid >> 6, lane = tid & 63;
  int xg = blockIdx.x;
  int ybase = xg * TILES;
  int cbb = xg * 64;
  const float* bias = b2 + cbb;
  int row0 = blockIdx.y * 128 + wave * 16;
  int m = lane & 15, q = lane >> 4;
  const unsigned short* arow0 = A + (size_t)(row0 + m) * 256 + q * 8;
  const unsigned short* arow1 = arow0 + 64 * 256;
  bf16x8 af0[8], af1[8];
#pragma unroll
  for (int k0i = 0; k0i < 8; ++k0i) {
    af0[k0i] = *(const bf16x8*)(arow0 + k0i * 32);
    af1[k0i] = *(const bf16x8*)(arow1 + k0i * 32);
  }
#pragma unroll
  for (int i = tid; i < TILES * 64 * 8; i += 256) {
    int k0i = i / (TILES * 64), r = i % (TILES * 64);
    *(us8*)(Bs + (size_t)k0i * TILES * 512 + (size_t)r * 8) =
        *(const us8*)(Bp + ((size_t)k0i * NT + ybase) * 512 + (size_t)r * 8);
  }
  __syncthreads();
  f32x4 acc[2][TILES];
#pragma unroll
  for (int h = 0; h < 2; h++)
#pragma unroll
    for (int i = 0; i < TILES; i++) acc[h][i] = (f32x4){0.f, 0.f, 0.f, 0.f};
#pragma unroll
  for (int k0i = 0; k0i < 8; ++k0i) {
    const unsigned short* bk = Bs + (size_t)k0i * TILES * 512 + lane * 8;
#pragma unroll
    for (int s = 0; s < TILES; ++s) {
      bf16x8 bfr = *(const bf16x8*)(bk + s * 512);
      acc[0][s] = __builtin_amdgcn_mfma_f32_16x16x32_bf16(bfr, af0[k0i], acc[0][s], 0, 0, 0);
      acc[1][s] = __builtin_amdgcn_mfma_f32_16x16x32_bf16(bfr, af1[k0i], acc[1][s], 0, 0, 0);
    }
  }
  int src0 = m + ((q & 1) ? 32 : 0);
#pragma unroll
  for (int h = 0; h < 2; h++) {
    int row = row0 + h * 64 + m;
#pragma unroll
    for (int p = 0; p < 2; p++) {
      f32x4 v0 = acc[h][2 * p], v1 = acc[h][2 * p + 1];
      f32x4 bb0 = *(const f32x4*)(bias + 32 * p + 4 * q);
      f32x4 bb1 = *(const f32x4*)(bias + 32 * p + 16 + 4 * q);
#pragma unroll
      for (int r = 0; r < 4; r++) {
        v0[r] = fmaxf(v0[r] + bb0[r], 0.f);
        v1[r] = fmaxf(v1[r] + bb1[r], 0.f);
      }
      unsigned long long d0 = pk64(v0), d1 = pk64(v1);
      unsigned long long a0 = __shfl(d0, src0, 64);
      unsigned long long b0 = __shfl(d0, src0 + 16, 64);
      unsigned long long a1 = __shfl(d1, src0, 64);
      unsigned long long b1v = __shfl(d1, src0 + 16, 64);
      unsigned long long lo = (q >> 1) ? a1 : a0;
      unsigned long long hi = (q >> 1) ? b1v : b0;
      if (row < NN) {
        size_t off = cbb + 32 * p + 8 * q;
        us8 rv = *(const us8*)(res1 + (size_t)row * 128 + off);
        unsigned long long ov[2] = { lo, hi };
        unsigned short* e = (unsigned short*)ov;
#pragma unroll
        for (int r = 0; r < 8; r++) e[r] = f2bf(bf2f(e[r]) + bf2f(rv[r]));
        *(us8*)(out_bf + (size_t)row * 256 + off) = *(const us8*)ov;
      }
    }
  }
}

// ---------------- GEMM3: A3 @ Bp3(NT=4) -> out f32 (+res2, sig8) ---------------
__global__ __launch_bounds__(256) void gemm3_kernel(
    const unsigned short* __restrict__ A,
    const unsigned short* __restrict__ Bp,
    const float* __restrict__ bias,
    const unsigned short* __restrict__ res2,   // stride 64
    float* __restrict__ out_f)                 // stride 64
{
  const int NT = 4, TILES = 4;
  __shared__ unsigned short Bs[TILES * 8 * 512];   // 32 KB
  int tid = threadIdx.x;
  int wave = tid >> 6, lane = tid & 63;
  int row0 = blockIdx.y * 64 + wave * 16;
  int m = lane & 15, q = lane >> 4;
  const unsigned short* arow = A + (size_t)(row0 + m) * 256 + q * 8;
  bf16x8 af[8];
#pragma unroll
  for (int k0i = 0; k0i < 8; ++k0i) af[k0i] = *(const bf16x8*)(arow + k0i * 32);
#pragma unroll
  for (int i = tid; i < TILES * 64 * 8; i += 256) {
    int k0i = i / (TILES * 64), r = i % (TILES * 64);
    *(us8*)(Bs + (size_t)k0i * TILES * 512 + (size_t)r * 8) =
        *(const us8*)(Bp + ((size_t)k0i * NT) * 512 + (size_t)r * 8);
  }
  __syncthreads();
  f32x4 acc[TILES];
#pragma unroll
  for (int i = 0; i < TILES; i++) acc[i] = (f32x4){0.f, 0.f, 0.f, 0.f};
#pragma unroll
  for (int k0i = 0; k0i < 8; ++k0i) {
    const unsigned short* bk = Bs + (size_t)k0i * TILES * 512 + lane * 8;
#pragma unroll
    for (int s = 0; s < TILES; ++s) {
      bf16x8 bfr = *(const bf16x8*)(bk + s * 512);
      acc[s] = __builtin_amdgcn_mfma_f32_16x16x32_bf16(bfr, af[k0i], acc[s], 0, 0, 0);
    }
  }
  int row = row0 + m;
  if (row >= NN) return;
  int cb = q * 4;
#pragma unroll
  for (int s = 0; s < TILES; ++s) {
    int col = s * 16 + cb;
    f32x4 v = acc[s];
    f32x4 bb = *(const f32x4*)(bias + col);
    us4 rv = *(const us4*)(res2 + (size_t)row * 64 + col);
#pragma unroll
    for (int r = 0; r < 4; r++) v[r] += bb[r] + bf2f(rv[r]);
    if (col < 8) {
#pragma unroll
      for (int r = 0; r < 4; r++) v[r] = 1.f / (1.f + __expf(-v[r]));
    }
    *(f32x4*)(out_f + (size_t)row * 64 + col) = v;
  }
}

extern "C" void kernel_launch(void* const* d_in, const int* in_sizes, int n_in,
                              void* d_out, int out_size, void* d_ws, size_t ws_size,
                              hipStream_t stream) {
  const float* z   = (const float*)d_in[0];
  const int*   edge = (const int*)d_in[1];
  const int*   srcn = edge;        // edge_index[0]
  const int*   dstn = edge + NE;   // edge_index[1]
  const float* w1n = (const float*)d_in[2];
  const float* w1r = (const float*)d_in[3];
  const float* b1  = (const float*)d_in[4];
  const float* w2n = (const float*)d_in[5];
  const float* w2r = (const float*)d_in[6];
  const float* b2  = (const float*)d_in[7];
  const float* wfn = (const float*)d_in[8];
  const float* wfr = (const float*)d_in[9];
  const float* bfb = (const float*)d_in[10];
  const float* wr1 = (const float*)d_in[11];
  const float* br1 = (const float*)d_in[12];
  const float* wr2 = (const float*)d_in[13];
  const float* br2 = (const float*)d_in[14];
  float* out = (float*)d_out;

  char* p = (char*)d_ws;
  auto alloc = [&](size_t bytes) { char* r = p; p += (bytes + 255) & ~255ull; return r; };
  int* rowoff = (int*)alloc((size_t)(NN + 1) * 4);
  int* bhist  = (int*)alloc((size_t)NB * 4);
  int* bucket_off = (int*)alloc((size_t)(NB + 1) * 4);
  int* gcur   = (int*)alloc((size_t)NB * 4);
  int* csr    = (int*)alloc((size_t)NE * 4);
  unsigned short* A1 = (unsigned short*)alloc((size_t)NN * 256 * 2);  // [mean1|z_bf], later reused as A3
  unsigned short* A2 = (unsigned short*)alloc((size_t)NN * 256 * 2);  // [mean2|h1]
  unsigned short* res1 = (unsigned short*)alloc((size_t)NN * 128 * 2);
  unsigned short* res2 = (unsigned short*)alloc((size_t)NN * 64 * 2);
  unsigned short* Bp1 = (unsigned short*)alloc(10240 * 8 * 2);
  unsigned short* Bp2 = (unsigned short*)alloc(4096 * 8 * 2);
  unsigned short* Bp3 = (unsigned short*)alloc(2048 * 8 * 2);
  unsigned short* A3 = A1;  // alias: A1 dead once gemm1 outputs land
  // ebuf aliases res1 (6.4 MB <= 12.8 MB): dead before gemm1 writes res1
  unsigned long long* ebuf = (unsigned long long*)res1;

  hipMemsetAsync(bhist, 0, (size_t)NB * 4, stream);
  // fused prologue: convz | prep | bhist
  setup_kernel<<<6442, 256, 0, stream>>>(z, A1, w1n, w1r, w2n, w2r, wfn, wfr, wr1, wr2,
                                         Bp1, Bp2, Bp3, dstn, bhist);
  bscan_kernel<<<1, 512, 0, stream>>>(bhist, bucket_off, gcur);
  bscat_kernel<<<128, 256, 0, stream>>>(srcn, dstn, bucket_off, gcur, ebuf);
  bfill_kernel<<<NB, 256, 0, stream>>>(ebuf, bucket_off, rowoff, csr);

  const int gy128 = (NN + 127) / 128;   // 391
  const int gy64  = (NN + 63) / 64;     // 782
  const int agg_blocks = (NN + 3) / 4;  // 12500

  // layer 1: mean1 = agg(z); fused GEMM -> h1 (A2 right), res1, res2 (bf16)
  agg_kernel<<<agg_blocks, 256, 0, stream>>>(A1 + 128, 256, A1, 256, rowoff, csr);
  gemm1_kernel<<<dim3(5, gy128), 256, 0, stream>>>(A1, Bp1, b1, br1, br2, A2 + 128, res1, res2);

  // layer 2: mean2 = agg(h1); h2 = relu([mean2|h1]@W2+b2) + res1 -> A3 right
  agg_kernel<<<agg_blocks, 256, 0, stream>>>(A2 + 128, 256, A2, 256, rowoff, csr);
  gemm2_kernel<<<dim3(2, gy128), 256, 0, stream>>>(A2, Bp2, b2, res1, A3 + 128);

  // layer 3: mean3 = agg(h2); out = [mean3|h2]@Wf+bf + res2, sigmoid cols 0..7
  agg_kernel<<<agg_blocks, 256, 0, stream>>>(A3 + 128, 256, A3, 256, rowoff, csr);
  gemm3_kernel<<<dim3(1, gy64), 256, 0, stream>>>(A3, Bp3, bfb, res2, out);
}